// Round 13
// baseline (308.079 us; speedup 1.0000x reference)
//
#include <hip/hip_runtime.h>
#include <stdint.h>

// Problem constants
#define B 8
#define N 2048
#define D 16
#define KNN 32
#define DM 256
#define CAP 96   // tie-fixup cap; degenerate all-tie batches still rank correctly

// ---------------------------------------------------------------------------
// K1: fused prep (arithmetic proven since round 5). Blocks 0..63: own-batch
// fp64 stats, then per-point masked x_crd row -> xcrd, sq, TT=(Tc,Tf).
// Block 64: W pack (float2 interleave, transposed) + pe bias/loss.
// ---------------------------------------------------------------------------
__global__ __launch_bounds__(256) void knn_prep(
    const float* __restrict__ x, const float* __restrict__ features,
    const float* __restrict__ Wc, const float* __restrict__ Wf,
    const float* __restrict__ pec, const float* __restrict__ pef,
    float* __restrict__ xcrd, float* __restrict__ sq,
    float2* __restrict__ TT, float2* __restrict__ Wpk,
    float* __restrict__ cbias, float* __restrict__ pe_loss_out)
{
    if (blockIdx.x == 64) {
        int dm = threadIdx.x;
        float cb = 0.f, al = 0.f;
#pragma unroll
        for (int p = 0; p < D; ++p)
            cb += pec[p * DM + dm] + pef[p * DM + dm];
#pragma unroll
        for (int p = 0; p < D; ++p)
            al += fabsf(pec[p * DM + dm]) + fabsf(pef[p * DM + dm]);
        cbias[dm] = cb;
#pragma unroll
        for (int k = 0; k < KNN; ++k)
            Wpk[k * DM + dm] = make_float2(Wc[dm * KNN + k], Wf[dm * KNN + k]);
        __shared__ float redf[256];
        redf[dm] = al; __syncthreads();
        for (int st = 128; st > 0; st >>= 1) {
            if (dm < st) redf[dm] += redf[dm + st];
            __syncthreads();
        }
        if (dm == 0) pe_loss_out[0] = redf[0];
        return;
    }

    int tid = threadIdx.x;
    int b = blockIdx.x >> 3;

    // ---- own-batch stats: 8 rows per thread, fp64 accumulate ----
    double ls[D], lq[D];
#pragma unroll
    for (int d = 0; d < D; ++d) { ls[d] = 0.0; lq[d] = 0.0; }
    for (int r = 0; r < 8; ++r) {
        const float* row = x + ((size_t)b * N + r * 256 + tid) * D;
#pragma unroll
        for (int d = 0; d < D; d += 4) {
            float4 v = *(const float4*)(row + d);
            double x0 = v.x, x1 = v.y, x2 = v.z, x3 = v.w;
            ls[d]   += x0; lq[d]   += x0 * x0;
            ls[d+1] += x1; lq[d+1] += x1 * x1;
            ls[d+2] += x2; lq[d+2] += x2 * x2;
            ls[d+3] += x3; lq[d+3] += x3 * x3;
        }
    }
#pragma unroll
    for (int d = 0; d < D; ++d) {
        double s = ls[d], q = lq[d];
#pragma unroll
        for (int st = 32; st >= 1; st >>= 1) {
            s += __shfl_xor(s, st, 64);
            q += __shfl_xor(q, st, 64);
        }
        ls[d] = s; lq[d] = q;
    }
    __shared__ double sred[4][2 * D];
    __shared__ float smean[32], sscale[32];
    int wave = tid >> 6, lane = tid & 63;
    if (lane == 0) {
#pragma unroll
        for (int d = 0; d < D; ++d) {
            sred[wave][d]     = ls[d];
            sred[wave][D + d] = lq[d];
        }
    }
    __syncthreads();
    if (tid < D) {
        int d = tid;
        double S = sred[0][d] + sred[1][d] + sred[2][d] + sred[3][d];
        double Q = sred[0][D+d] + sred[1][D+d] + sred[2][D+d] + sred[3][D+d];
        double mean = S / (double)N;
        double var  = (Q - S * S / (double)N) / (double)(N - 1);
        if (var < 0.0) var = 0.0;
        float stdv = (float)sqrt(var);
        float scl  = 1.0f / (stdv + 1e-5f);
        float scl0 = 1.0f / (0.0f + 1e-5f);
        bool mask = features[b * D + d] > 0.1f;
        smean [d]      = mask ? 0.0f : (float)mean;
        sscale[d]      = mask ? scl0 : scl;
        smean [16 + d] = mask ? (float)mean : 0.0f;
        sscale[16 + d] = mask ? scl : scl0;
    }
    __syncthreads();

    // ---- per-point processing (identical arithmetic to rounds 1-12) ----
    int t = blockIdx.x * 256 + tid;
    float tc = 0.f, tf = 0.f, s = 0.f;
    float row[D];
#pragma unroll
    for (int d = 0; d < D; ++d) {
        float xv = x[(size_t)t * D + d];
        bool mask = features[b * D + d] > 0.1f;
        float xc = mask ? 0.f : xv;
        float xf = mask ? xv : 0.f;
        row[d] = xc;
        s += xc * xc;                            // sequential, mirrors ref sq
        float vc = (xc - smean[d])      * sscale[d];
        vc = fminf(10.f, fmaxf(-10.f, vc));
        float vf = (xf - smean[16 + d]) * sscale[16 + d];
        vf = fminf(10.f, fmaxf(-10.f, vf));
        tc += vc; tf += vf;
    }
#pragma unroll
    for (int d = 0; d < D; d += 4)
        *(float4*)(xcrd + (size_t)t * D + d) =
            make_float4(row[d], row[d+1], row[d+2], row[d+3]);
    sq[t] = s; TT[t] = make_float2(tc, tf);
}

// ---------------------------------------------------------------------------
// K2: one wave (one 64-thread block) per query.
//  Fill: direct L2 reads, distance bit-path byte-identical to round 12.
//  Selection: EXACT bit-radix select of tau = 32nd-smallest distance-bits
//  over the wave's 2048 candidates — 31 MSB-first rounds of
//  (32x v_cmp -> __ballot -> s_bcnt scalar count) with a wave-uniform
//  threshold.  No sort, no shuffles, no register copy.  Invariant: p is the
//  largest prefix with count(v < p) < 32; terminates with p == tau bits.
//  Tie-fixup + unique-key ranking (proven round 8/12) unchanged.
//  Matvec reads packed float2 W / TT (half the VMEM instructions).
// ---------------------------------------------------------------------------
__global__ __launch_bounds__(64, 4) void knn_main(
    const float* __restrict__ xcrd, const float* __restrict__ sq,
    const float2* __restrict__ TT, const float2* __restrict__ Wpk,
    const float* __restrict__ cbias, float* __restrict__ out)
{
    __shared__ unsigned long long collect[CAP];  // 768 B
    __shared__ int sortedm[KNN];                 // 128 B

    const int lane = threadIdx.x;
    const int qid  = blockIdx.x;                 // 0..16383
    const int b = qid >> 11;
    const int n = qid & (N - 1);

    const float* xb  = xcrd + (size_t)b * N * D;
    const float* sqb = sq + b * N;

    // query row
    float qx[D];
#pragma unroll
    for (int d = 0; d < D; d += 4) {
        float4 v = *(const float4*)(xb + (size_t)n * D + d);
        qx[d] = v.x; qx[d+1] = v.y; qx[d+2] = v.z; qx[d+3] = v.w;
    }
    const float sqn = sqb[n];

    // ---- fill: round-12 distance arithmetic, bits kept in registers ----
    uint32_t vb[KNN];
#pragma unroll
    for (int j = 0; j < KNN; ++j) {
        int m = j * 64 + lane;
        const float* xm = xb + (size_t)m * D;
        float4 v0 = *(const float4*)(xm);
        float4 v1 = *(const float4*)(xm + 4);
        float4 v2 = *(const float4*)(xm + 8);
        float4 v3 = *(const float4*)(xm + 12);
        float dot = 0.f;
        dot += qx[0]  * v0.x; dot += qx[1]  * v0.y;
        dot += qx[2]  * v0.z; dot += qx[3]  * v0.w;
        dot += qx[4]  * v1.x; dot += qx[5]  * v1.y;
        dot += qx[6]  * v1.z; dot += qx[7]  * v1.w;
        dot += qx[8]  * v2.x; dot += qx[9]  * v2.y;
        dot += qx[10] * v2.z; dot += qx[11] * v2.w;
        dot += qx[12] * v3.x; dot += qx[13] * v3.y;
        dot += qx[14] * v3.z; dot += qx[15] * v3.w;
        float d2 = sqn + sqb[m] - 2.0f * dot;
        float dist = fabsf(sqrtf(fmaxf(d2, 0.f)));   // fabs: -0 -> +0
        vb[j] = __float_as_uint(dist);               // sign bit always 0
    }

    // ---- exact bit-radix select: tau_bits = 32nd smallest of 2048 ----
    uint32_t p = 0;
#pragma unroll 1
    for (int bit = 30; bit >= 0; --bit) {
        uint32_t t = p | (1u << bit);
        int c = 0;
#pragma unroll
        for (int j = 0; j < KNN; ++j)
            c += (int)__popcll(__ballot(vb[j] < t));
        if (c < KNN) p = t;          // wave-uniform scalar update
    }
    const uint32_t taub = p;         // exact 32nd-smallest distance bits

    // ---- tie-fixup: compact all dist <= tau in ascending global-index order ----
    const unsigned long long lmask = (1ULL << lane) - 1ULL;
    int base = 0;
#pragma unroll
    for (int j = 0; j < KNN; ++j) {
        bool f = (vb[j] <= taub);
        unsigned long long mk = __ballot(f);
        if (f) {
            int pos = base + (int)__popcll(mk & lmask);
            if (pos < CAP)
                collect[pos] =
                    (((unsigned long long)vb[j]) << 11)
                    | (unsigned)(j * 64 + lane);
        }
        base += (int)__popcll(mk);
    }
    int T = base < CAP ? base : CAP;             // wave-uniform, >= 32
    __syncthreads();

    // ---- rank the T collected items (keys globally unique) ----
#pragma unroll 1
    for (int slot = 0; slot < 2; ++slot) {
        int i = lane + slot * 64;
        if (i < T) {
            unsigned long long mk = collect[i];
            int rank = 0;
#pragma unroll 1
            for (int t2 = 0; t2 < T; ++t2)
                rank += (collect[t2] < mk) ? 1 : 0;
            if (rank < KNN)
                sortedm[rank] = (int)(mk & 2047u);
        }
    }
    __syncthreads();

    // ---- matvec: ranked top-32, packed float2 operands ----
    float acc[4] = {0.f, 0.f, 0.f, 0.f};
    const float2* TTb = TT + b * N;
    const float2 ttn = TTb[n];
    const float Tcn = ttn.x, Tfn = ttn.y;

#pragma unroll
    for (int k = 0; k < KNN; ++k) {
        int wm = sortedm[k];
        float2 tv = TTb[wm];
        float ak = tv.x - Tcn;
        float bk = tv.y - Tfn;
        const float2* wp = Wpk + k * DM + lane;
#pragma unroll
        for (int q = 0; q < 4; ++q) {
            float2 w = wp[q * 64];
            acc[q] += w.x * ak + w.y * bk;
        }
    }

    size_t obase = (size_t)qid * DM + lane;
#pragma unroll
    for (int q = 0; q < 4; ++q)
        out[obase + q * 64] = acc[q] + cbias[lane + q * 64];
}

// ---------------------------------------------------------------------------
extern "C" void kernel_launch(void* const* d_in, const int* in_sizes, int n_in,
                              void* d_out, int out_size, void* d_ws, size_t ws_size,
                              hipStream_t stream)
{
    const float* x        = (const float*)d_in[0];   // (B,N,D)
    const float* features = (const float*)d_in[1];   // (B,D)
    const float* W_crd    = (const float*)d_in[2];   // (DM,K)
    const float* W_ftr    = (const float*)d_in[3];   // (DM,K)
    const float* pe_crd   = (const float*)d_in[4];   // (1,1,D,DM)
    const float* pe_ftr   = (const float*)d_in[5];   // (1,1,D,DM)
    // d_in[6] = k (constant 32), ignored

    float* out = (float*)d_out;                      // B*N*DM floats + 1 (pe_loss)

    float*  xcrd = (float*)d_ws;                     // 262144 floats
    float*  sqv  = xcrd + (size_t)B * N * D;         // 16384
    float2* TT   = (float2*)(sqv + B * N);           // 16384 float2 (8B-aligned)
    float2* Wpk  = TT + B * N;                       // 8192 float2
    float*  cbias = (float*)(Wpk + KNN * DM);        // 256

    knn_prep<<<65, 256, 0, stream>>>(x, features, W_crd, W_ftr, pe_crd, pe_ftr,
                                     xcrd, sqv, TT, Wpk, cbias,
                                     out + (size_t)out_size - 1);
    knn_main<<<B * N, 64, 0, stream>>>(xcrd, sqv, TT, Wpk, cbias, out);
}